// Round 5
// baseline (183.894 us; speedup 1.0000x reference)
//
#include <hip/hip_runtime.h>
#include <math.h>

// Problem constants (fixed by the reference)
#define BB   64
#define NN   131072
#define KTAPS 5
#define TILE 1024          // elements per chunk (256 threads x 4)
#define CHUNKS 4
#define SPAN (TILE * CHUNKS)   // 4096 elements per block
#define NTHREADS 256

// 2*pi / sampling_freq
#define ANG_PER_HZ 2.0453077171808549e-7f   // float(2*pi/30720000.0)
// 10*log10(1.5)
#define EBNO_OFF   1.7609125905568124f
// log2(10)/20
#define L2TEN_OVER20 0.16609640474436813f

typedef float f32x4 __attribute__((ext_vector_type(4)));

struct Buf {
    float2 xrL, xrR, xiL, xiR;   // halo pairs: x[base-2..base-1], x[base+4..base+5]
    float4 xr0, xi0, nr, ni;     // body + noise
};

__device__ __forceinline__ Buf load_chunk(const float* __restrict__ xr,
                                          const float* __restrict__ xi,
                                          const float* __restrict__ nr,
                                          const float* __restrict__ ni,
                                          int base) {
    // Clamp halo addresses at row ends (values masked to 0 in compute).
    const int aL = (base == 0)      ? 0      : base - 2;
    const int aR = (base == NN - 4) ? NN - 2 : base + 4;
    Buf b;
    b.xrL = *reinterpret_cast<const float2*>(xr + aL);
    b.xr0 = *reinterpret_cast<const float4*>(xr + base);
    b.xrR = *reinterpret_cast<const float2*>(xr + aR);
    b.xiL = *reinterpret_cast<const float2*>(xi + aL);
    b.xi0 = *reinterpret_cast<const float4*>(xi + base);
    b.xiR = *reinterpret_cast<const float2*>(xi + aR);
    b.nr  = *reinterpret_cast<const float4*>(nr + base);
    b.ni  = *reinterpret_cast<const float4*>(ni + base);
    return b;
}

__device__ __forceinline__ void compute_store(
    const Buf& v, int base, float ang, float sA, float cA, float scale,
    const float* tr, const float* ti, float* __restrict__ outr,
    float* __restrict__ outi) {
    // trig anchor for this chunk (independent of the loads)
    float s, c;
    sincosf(ang * (float)(base - 2), &s, &c);

    const bool lok = (base != 0);
    const bool rok = (base != NN - 4);

    // window x[base-2 .. base+5]
    float ur[8], ui[8];
    ur[0] = lok ? v.xrL.x : 0.0f;  ui[0] = lok ? v.xiL.x : 0.0f;
    ur[1] = lok ? v.xrL.y : 0.0f;  ui[1] = lok ? v.xiL.y : 0.0f;
    ur[2] = v.xr0.x;  ui[2] = v.xi0.x;
    ur[3] = v.xr0.y;  ui[3] = v.xi0.y;
    ur[4] = v.xr0.z;  ui[4] = v.xi0.z;
    ur[5] = v.xr0.w;  ui[5] = v.xi0.w;
    ur[6] = rok ? v.xrR.x : 0.0f;  ui[6] = rok ? v.xiR.x : 0.0f;
    ur[7] = rok ? v.xrR.y : 0.0f;  ui[7] = rok ? v.xiR.y : 0.0f;

    // CFO rotation via angle-addition recurrence (phase = ang*(base-2+j))
    float wr[8], wi[8];
#pragma unroll
    for (int j = 0; j < 8; ++j) {
        wr[j] = ur[j] * c - ui[j] * s;
        wi[j] = ur[j] * s + ui[j] * c;
        float cn = c * cA - s * sA;
        float sn = s * cA + c * sA;
        c = cn; s = sn;
    }

    // 5-tap complex conv (cross-correlation) + AWGN
    const float nr_[4] = {v.nr.x, v.nr.y, v.nr.z, v.nr.w};
    const float ni_[4] = {v.ni.x, v.ni.y, v.ni.z, v.ni.w};

    f32x4 yr4, yi4;
#pragma unroll
    for (int j = 0; j < 4; ++j) {
        float ar = 0.0f, ai = 0.0f;
#pragma unroll
        for (int k = 0; k < KTAPS; ++k) {
            ar = fmaf(tr[k], wr[j + k], ar);
            ar = fmaf(-ti[k], wi[j + k], ar);
            ai = fmaf(ti[k], wr[j + k], ai);
            ai = fmaf(tr[k], wi[j + k], ai);
        }
        yr4[j] = fmaf(nr_[j], scale, ar);
        yi4[j] = fmaf(ni_[j], scale, ai);
    }

    __builtin_nontemporal_store(yr4, reinterpret_cast<f32x4*>(outr + base));
    __builtin_nontemporal_store(yi4, reinterpret_cast<f32x4*>(outi + base));
}

__global__ __launch_bounds__(NTHREADS) void wc_kernel(
    const float* __restrict__ x_real,  const float* __restrict__ x_imag,
    const float* __restrict__ ebno_db, const float* __restrict__ cfo_u,
    const float* __restrict__ taps_real, const float* __restrict__ taps_imag,
    const float* __restrict__ noise_real, const float* __restrict__ noise_imag,
    float* __restrict__ out)
{
    const int b     = blockIdx.y;
    const int base0 = blockIdx.x * SPAN + threadIdx.x * 4;
    const size_t rowoff = (size_t)b * NN;

    const float* __restrict__ xr = x_real + rowoff;
    const float* __restrict__ xi = x_imag + rowoff;
    const float* __restrict__ nr = noise_real + rowoff;
    const float* __restrict__ ni = noise_imag + rowoff;
    float* __restrict__ outr = out + rowoff;
    float* __restrict__ outi = out + (size_t)BB * NN + rowoff;

    // ---- issue chunk 0 loads first; scalars resolve under their latency ----
    Buf A = load_chunk(xr, xi, nr, ni, base0);

    // ---- per-batch scalars (block-uniform) ----
    const float cfo     = cfo_u[b];
    const float delta_f = (cfo * 2.0f - 1.0f) * 0.05f * 15000.0f;
    const float ang     = delta_f * ANG_PER_HZ;        // radians per sample
    const float snr     = ebno_db[b] + EBNO_OFF;
    const float scale   = 0.5f * exp2f(-snr * L2TEN_OVER20);

    float tr[KTAPS], ti[KTAPS];
#pragma unroll
    for (int k = 0; k < KTAPS; ++k) {
        tr[k] = taps_real[b * KTAPS + k];
        ti[k] = taps_imag[b * KTAPS + k];
    }

    float sA, cA;
    sincosf(ang, &sA, &cA);

    // ---- 2-deep pipelined chunk loop: loads of c+1 in flight during compute of c
    Buf B;
#pragma unroll
    for (int c = 0; c < CHUNKS; ++c) {
        if (c + 1 < CHUNKS)
            B = load_chunk(xr, xi, nr, ni, base0 + (c + 1) * TILE);
        compute_store(A, base0 + c * TILE, ang, sA, cA, scale, tr, ti, outr, outi);
        A = B;
    }
}

extern "C" void kernel_launch(void* const* d_in, const int* in_sizes, int n_in,
                              void* d_out, int out_size, void* d_ws, size_t ws_size,
                              hipStream_t stream) {
    const float* x_real     = (const float*)d_in[0];
    const float* x_imag     = (const float*)d_in[1];
    const float* ebno_db    = (const float*)d_in[2];
    const float* cfo_u      = (const float*)d_in[3];
    const float* taps_real  = (const float*)d_in[4];
    const float* taps_imag  = (const float*)d_in[5];
    const float* noise_real = (const float*)d_in[6];
    const float* noise_imag = (const float*)d_in[7];

    dim3 grid(NN / SPAN, BB);
    wc_kernel<<<grid, NTHREADS, 0, stream>>>(
        x_real, x_imag, ebno_db, cfo_u, taps_real, taps_imag,
        noise_real, noise_imag, (float*)d_out);
}